// Round 4
// baseline (223.720 us; speedup 1.0000x reference)
//
#include <hip/hip_runtime.h>
#include <stdint.h>
#include <stddef.h>

#define DIM 1024
#define EPS 1e-8f

typedef __attribute__((ext_vector_type(8))) __bf16 bf16x8;
typedef __attribute__((ext_vector_type(4))) float f32x4;

__device__ __forceinline__ unsigned short f32_to_bf16(float f) {
    unsigned int u = __float_as_uint(f);
    u += 0x7FFFu + ((u >> 16) & 1u);   // round-to-nearest-even
    return (unsigned short)(u >> 16);
}

// async global->LDS, 16B per lane, wave-uniform LDS base + lane*16
__device__ __forceinline__ void async_copy16(const void* g, void* l) {
    __builtin_amdgcn_global_load_lds(
        (__attribute__((address_space(1))) void*)const_cast<void*>(g),
        (__attribute__((address_space(3))) void*)(l), 16, 0, 0);
}

// fine-grained pipeline sync: drain all but the newest N vmem ops, then
// barrier. N=4 keeps one full stage (4 glds) in flight across the barrier.
#define PIPE_SYNC(N) asm volatile("s_waitcnt vmcnt(" #N ")\n\ts_barrier" ::: "memory")

// ---------------------------------------------------------------------------
// Prep (merged x/pos + neg): wave-per-row, no barriers. Unit-normalized bf16
// rows; x-rows also emit exact fp32 positive cosine sim and zero rowsum[row].
// ---------------------------------------------------------------------------
__global__ __launch_bounds__(256)
void prep_all(const float* __restrict__ x, const float* __restrict__ pos,
              const float* __restrict__ neg,
              unsigned short* __restrict__ Xn, unsigned short* __restrict__ Nn,
              float* __restrict__ simOut, float* __restrict__ rowsum, int bn) {
    const int lane = threadIdx.x & 63;
    const int wave = threadIdx.x >> 6;
    const int grow = blockIdx.x * 4 + wave;
    const bool isX = grow < bn;
    const int row  = isX ? grow : grow - bn;
    const float* src = isX ? x : neg;
    unsigned short* dst = isX ? Xn : Nn;

    const float4* s = (const float4*)(src + (size_t)row * DIM);
    float4 xv[4], pv[4];
    float sxx = 0.f, spp = 0.f, sxp = 0.f;
#pragma unroll
    for (int i = 0; i < 4; i++) {
        xv[i] = s[lane + 64 * i];
        sxx += xv[i].x * xv[i].x + xv[i].y * xv[i].y + xv[i].z * xv[i].z + xv[i].w * xv[i].w;
    }
    if (isX) {
        const float4* p = (const float4*)(pos + (size_t)row * DIM);
#pragma unroll
        for (int i = 0; i < 4; i++) {
            pv[i] = p[lane + 64 * i];
            spp += pv[i].x * pv[i].x + pv[i].y * pv[i].y + pv[i].z * pv[i].z + pv[i].w * pv[i].w;
            sxp += xv[i].x * pv[i].x + xv[i].y * pv[i].y + xv[i].z * pv[i].z + xv[i].w * pv[i].w;
        }
#pragma unroll
        for (int off = 1; off < 64; off <<= 1) {
            sxx += __shfl_xor(sxx, off);
            spp += __shfl_xor(spp, off);
            sxp += __shfl_xor(sxp, off);
        }
    } else {
#pragma unroll
        for (int off = 1; off < 64; off <<= 1) sxx += __shfl_xor(sxx, off);
    }
    const float nx  = sqrtf(sxx);
    const float inv = (nx > 0.f) ? (1.f / nx) : 0.f;
    if (isX && lane == 0) {
        const float np = sqrtf(spp);
        simOut[row] = sxp / fmaxf(nx * np, EPS);
        rowsum[row] = 0.f;
    }
    ushort4* d = (ushort4*)(dst + (size_t)row * DIM);
#pragma unroll
    for (int i = 0; i < 4; i++) {
        ushort4 o;
        o.x = f32_to_bf16(xv[i].x * inv);
        o.y = f32_to_bf16(xv[i].y * inv);
        o.z = f32_to_bf16(xv[i].z * inv);
        o.w = f32_to_bf16(xv[i].w * inv);
        d[lane + 64 * i] = o;
    }
}

// ---------------------------------------------------------------------------
// Fused GEMM: rowsum[i] += sum_j exp( Xn[i,:] . Nn[j,:] )  (unit rows, bf16)
// 128x128 tile, BK=32, 3-stage LDS pipeline (48 KB), prefetch distance 2.
// XCD-aware block swizzle: flat&7 = XCD (round-robin dispatch assumption).
// Each XCD owns an 8-column panel of N-tiles (2 MB -> resident in its 4 MB
// L2) and sweeps row-strips with the 8 columns innermost (X-strip shared by
// 8 temporally-adjacent blocks on the same XCD). Turns the 1 GB staging
// stream from an L3-bound (~8 TB/s) into an L2-served (~34 TB/s) stream.
// ---------------------------------------------------------------------------
__global__ __launch_bounds__(256)
void gemm_exp_rowsum(const unsigned short* __restrict__ Xn,
                     const unsigned short* __restrict__ Nn,
                     float* __restrict__ rowsum) {
    constexpr int K    = DIM;        // 1024
    constexpr int BK   = 32;         // k-elements per stage (64 B per row)
    constexpr int BUFE = 128 * BK;   // elements per buffer (8 KB)
    __shared__ __align__(16) unsigned short Ash[3][BUFE];
    __shared__ __align__(16) unsigned short Bsh[3][BUFE];

    const int tid  = threadIdx.x;
    const int lane = tid & 63;
    const int wave = tid >> 6;

    // XCD swizzle: grid is 1D (2048). xcd = flat&7; within-XCD index 0..255
    // maps to (rowT 0..31 outer, col_in 0..7 inner); colT = xcd*8 + col_in.
    const int flat = blockIdx.x;
    const int xcd  = flat & 7;
    const int idx  = flat >> 3;
    const int rowBase = (idx >> 3) * 128;
    const int colBase = (xcd * 8 + (idx & 7)) * 128;

    // staging map: one glds instr = 1KB = 16 rows x 64B; lane -> (row, chunk)
    const int srow   = lane >> 2;                         // 0..15
    const int schunk = (lane & 3) ^ ((srow >> 1) & 3);    // global-side swizzle
    const unsigned short* gA = Xn + (size_t)(rowBase + wave * 16 + srow) * K + schunk * 8;
    const unsigned short* gB = Nn + (size_t)(colBase + wave * 16 + srow) * K + schunk * 8;
    const int lgrp0 = (wave * 16) * BK;        // wave's 16-row group
    const int lgrp1 = (wave * 16 + 64) * BK;   // +64 rows group

    const f32x4 fz = {0.f, 0.f, 0.f, 0.f};
    f32x4 acc[4][4];
#pragma unroll
    for (int mi = 0; mi < 4; mi++)
#pragma unroll
        for (int ni = 0; ni < 4; ni++) acc[mi][ni] = fz;

    const int m0   = (wave >> 1) * 64;
    const int n0   = (wave & 1) * 64;
    const int quad = lane >> 4;
    const int mrow = lane & 15;
    const int ckx  = (quad ^ ((mrow >> 1) & 3)) * 8;   // physical chunk (ushorts)

    int aoff[4], boff[4];
#pragma unroll
    for (int i = 0; i < 4; i++) {
        aoff[i] = (m0 + i * 16 + mrow) * BK + ckx;
        boff[i] = (n0 + i * 16 + mrow) * BK + ckx;
    }

#define STAGE(buf, kq)                                                   \
    do {                                                                 \
        async_copy16(gA + (kq),          &Ash[buf][lgrp0]);              \
        async_copy16(gA + 64 * K + (kq), &Ash[buf][lgrp1]);              \
        async_copy16(gB + (kq),          &Bsh[buf][lgrp0]);              \
        async_copy16(gB + 64 * K + (kq), &Bsh[buf][lgrp1]);              \
    } while (0)

#define COMPUTE(buf)                                                     \
    do {                                                                 \
        bf16x8 af[4], bf[4];                                             \
        _Pragma("unroll")                                                \
        for (int i = 0; i < 4; i++) {                                    \
            af[i] = *(const bf16x8*)&Ash[buf][aoff[i]];                  \
            bf[i] = *(const bf16x8*)&Bsh[buf][boff[i]];                  \
        }                                                                \
        _Pragma("unroll")                                                \
        for (int mi = 0; mi < 4; mi++)                                   \
            _Pragma("unroll")                                            \
            for (int ni = 0; ni < 4; ni++)                               \
                acc[mi][ni] = __builtin_amdgcn_mfma_f32_16x16x32_bf16(   \
                    af[mi], bf[ni], acc[mi][ni], 0, 0, 0);               \
    } while (0)

    STAGE(0, 0);
    STAGE(1, BK);
    int kq = 2 * BK;
    // phases 0..29 (10 x 3), buffer index = phase % 3, stage runs 2 ahead
    for (int it = 0; it < 10; it++) {
        PIPE_SYNC(4); STAGE(2, kq);          COMPUTE(0);
        PIPE_SYNC(4); STAGE(0, kq + BK);     COMPUTE(1);
        PIPE_SYNC(4); STAGE(1, kq + 2 * BK); COMPUTE(2);
        kq += 3 * BK;
    }
    PIPE_SYNC(4); COMPUTE(0);   // phase 30
    PIPE_SYNC(0); COMPUTE(1);   // phase 31 (drain last stage)
#undef STAGE
#undef COMPUTE

    // epilogue: exp + row-reduce. C/D layout: col=lane&15, row=quad*4+reg.
#pragma unroll
    for (int mi = 0; mi < 4; mi++) {
        float rs0 = 0.f, rs1 = 0.f, rs2 = 0.f, rs3 = 0.f;
#pragma unroll
        for (int ni = 0; ni < 4; ni++) {
            rs0 += __expf(acc[mi][ni].x);
            rs1 += __expf(acc[mi][ni].y);
            rs2 += __expf(acc[mi][ni].z);
            rs3 += __expf(acc[mi][ni].w);
        }
#pragma unroll
        for (int off = 1; off < 16; off <<= 1) {   // reduce over 16 cols
            rs0 += __shfl_xor(rs0, off);
            rs1 += __shfl_xor(rs1, off);
            rs2 += __shfl_xor(rs2, off);
            rs3 += __shfl_xor(rs3, off);
        }
        if ((lane & 15) == 0) {
            const int r = rowBase + m0 + mi * 16 + quad * 4;
            atomicAdd(&rowsum[r + 0], rs0);
            atomicAdd(&rowsum[r + 1], rs1);
            atomicAdd(&rowsum[r + 2], rs2);
            atomicAdd(&rowsum[r + 3], rs3);
        }
    }
}

__global__ __launch_bounds__(1024)
void loss_kernel(const float* __restrict__ rowsum, const float* __restrict__ sim,
                 float* __restrict__ out, int bn) {
    const int tid  = threadIdx.x;
    const int lane = tid & 63;
    const int wave = tid >> 6;
    float acc = 0.f;
    for (int i = tid; i < bn; i += 1024) acc += logf(rowsum[i]) - sim[i];
#pragma unroll
    for (int off = 1; off < 64; off <<= 1) acc += __shfl_xor(acc, off);
    __shared__ float red[16];
    if (lane == 0) red[wave] = acc;
    __syncthreads();
    if (tid == 0) {
        float t = 0.f;
#pragma unroll
        for (int i = 0; i < 16; i++) t += red[i];
        out[0] = t / (float)bn;
    }
}

extern "C" void kernel_launch(void* const* d_in, const int* in_sizes, int n_in,
                              void* d_out, int out_size, void* d_ws, size_t ws_size,
                              hipStream_t stream) {
    const float* x   = (const float*)d_in[0];
    const float* pos = (const float*)d_in[1];
    const float* neg = (const float*)d_in[2];
    const int bn = in_sizes[0] / DIM;  // 4096
    const int cn = in_sizes[2] / DIM;  // 8192

    // ws layout: Xn bf16 [bn*DIM] | Nn bf16 [cn*DIM] | sim f32 [bn] | rowsum f32 [bn]
    unsigned short* Xn = (unsigned short*)d_ws;
    unsigned short* Nn = Xn + (size_t)bn * DIM;
    float* sim    = (float*)(Nn + (size_t)cn * DIM);
    float* rowsum = sim + bn;

    prep_all<<<dim3((bn + cn) / 4), dim3(256), 0, stream>>>(x, pos, neg, Xn, Nn, sim, rowsum, bn);
    gemm_exp_rowsum<<<dim3((cn / 128) * (bn / 128)), dim3(256), 0, stream>>>(Xn, Nn, rowsum);
    loss_kernel<<<dim3(1), dim3(1024), 0, stream>>>(rowsum, sim, (float*)d_out, bn);
}

// Round 5
// 180.148 us; speedup vs baseline: 1.2419x; 1.2419x over previous
//
#include <hip/hip_runtime.h>
#include <stdint.h>
#include <stddef.h>

#define DIM 1024
#define EPS 1e-8f

typedef __attribute__((ext_vector_type(4))) float f32x4;

// async global->LDS, 16B per lane, wave-uniform LDS base + lane*16
__device__ __forceinline__ void async_copy16(const void* g, void* l) {
    __builtin_amdgcn_global_load_lds(
        (__attribute__((address_space(1))) void*)const_cast<void*>(g),
        (__attribute__((address_space(3))) void*)(l), 16, 0, 0);
}

// drain all but newest N vmem ops, then barrier (compiler may still add its
// own vmcnt(0) — kept because it is never worse than __syncthreads)
#define PIPE_SYNC(N) asm volatile("s_waitcnt vmcnt(" #N ")\n\ts_barrier" ::: "memory")

// ---------------------------------------------------------------------------
// Prep: wave-per-row. Unit-normalize, scale by 16 (power of 2, undone in the
// GEMM epilogue), cast to OCP fp8 e4m3 via cvt_pk. x-rows also emit exact
// fp32 positive cosine sim and zero rowsum[row]. fp8 row = 1024 B = 1 uint4
// per lane.
// ---------------------------------------------------------------------------
__global__ __launch_bounds__(256)
void prep_all(const float* __restrict__ x, const float* __restrict__ pos,
              const float* __restrict__ neg,
              unsigned char* __restrict__ Xn, unsigned char* __restrict__ Nn,
              float* __restrict__ simOut, float* __restrict__ rowsum, int bn) {
    const int lane = threadIdx.x & 63;
    const int wave = threadIdx.x >> 6;
    const int grow = blockIdx.x * 4 + wave;
    const bool isX = grow < bn;
    const int row  = isX ? grow : grow - bn;
    const float* src = isX ? x : neg;
    unsigned char* dst = isX ? Xn : Nn;

    const float4* s = (const float4*)(src + (size_t)row * DIM);
    float4 xv[4], pv[4];
    float sxx = 0.f, spp = 0.f, sxp = 0.f;
#pragma unroll
    for (int i = 0; i < 4; i++) {
        xv[i] = s[lane + 64 * i];
        sxx += xv[i].x * xv[i].x + xv[i].y * xv[i].y + xv[i].z * xv[i].z + xv[i].w * xv[i].w;
    }
    if (isX) {
        const float4* p = (const float4*)(pos + (size_t)row * DIM);
#pragma unroll
        for (int i = 0; i < 4; i++) {
            pv[i] = p[lane + 64 * i];
            spp += pv[i].x * pv[i].x + pv[i].y * pv[i].y + pv[i].z * pv[i].z + pv[i].w * pv[i].w;
            sxp += xv[i].x * pv[i].x + xv[i].y * pv[i].y + xv[i].z * pv[i].z + xv[i].w * pv[i].w;
        }
#pragma unroll
        for (int off = 1; off < 64; off <<= 1) {
            sxx += __shfl_xor(sxx, off);
            spp += __shfl_xor(spp, off);
            sxp += __shfl_xor(sxp, off);
        }
    } else {
#pragma unroll
        for (int off = 1; off < 64; off <<= 1) sxx += __shfl_xor(sxx, off);
    }
    const float nx  = sqrtf(sxx);
    const float inv = (nx > 0.f) ? (16.f / nx) : 0.f;   // x16 -> e4m3 sweet spot
    if (isX && lane == 0) {
        const float np = sqrtf(spp);
        simOut[row] = sxp / fmaxf(nx * np, EPS);
        rowsum[row] = 0.f;
    }
    uint4 w;
    unsigned int t;
    t = __builtin_amdgcn_cvt_pk_fp8_f32(xv[0].x * inv, xv[0].y * inv, 0, false);
    w.x = __builtin_amdgcn_cvt_pk_fp8_f32(xv[0].z * inv, xv[0].w * inv, t, true);
    t = __builtin_amdgcn_cvt_pk_fp8_f32(xv[1].x * inv, xv[1].y * inv, 0, false);
    w.y = __builtin_amdgcn_cvt_pk_fp8_f32(xv[1].z * inv, xv[1].w * inv, t, true);
    t = __builtin_amdgcn_cvt_pk_fp8_f32(xv[2].x * inv, xv[2].y * inv, 0, false);
    w.z = __builtin_amdgcn_cvt_pk_fp8_f32(xv[2].z * inv, xv[2].w * inv, t, true);
    t = __builtin_amdgcn_cvt_pk_fp8_f32(xv[3].x * inv, xv[3].y * inv, 0, false);
    w.w = __builtin_amdgcn_cvt_pk_fp8_f32(xv[3].z * inv, xv[3].w * inv, t, true);
    // lane i owns elements [i*16, i*16+16) = bytes [i*16, i*16+16) of the row
    ((uint4*)(dst + (size_t)row * DIM))[lane] = w;
}

// ---------------------------------------------------------------------------
// Fused fp8 GEMM: rowsum[i] += sum_j exp( (Xn8[i]/16 . Nn8[j]/16) )
// 128x128 tile, fp8 BK=64 (64 B rows), 3-stage LDS (24 KB total), prefetch
// distance 2. Per phase: 2 k-steps x 16 mfma_f32_16x16x32_fp8_fp8.
// Swizzle: rows are 64 B = 4 x 16B chunks; bank pattern wraps every 2 rows,
// XOR key (row>>1)&3 (verified conflict-free in R3/R4 counters).
// ---------------------------------------------------------------------------
__global__ __launch_bounds__(256)
void gemm_exp_rowsum(const unsigned char* __restrict__ Xn,
                     const unsigned char* __restrict__ Nn,
                     float* __restrict__ rowsum) {
    constexpr int KB   = DIM;        // 1024 bytes per fp8 row
    constexpr int BK   = 64;         // 64 B = 64 fp8 elems per stage-row
    constexpr int BUFB = 128 * BK;   // 8 KB per buffer
    __shared__ __align__(16) unsigned char Ash[3][BUFB];
    __shared__ __align__(16) unsigned char Bsh[3][BUFB];

    const int tid  = threadIdx.x;
    const int lane = tid & 63;
    const int wave = tid >> 6;
    const int rowBase = blockIdx.y * 128;
    const int colBase = blockIdx.x * 128;

    // staging: one glds = 1 KB = 16 rows x 64 B; lane -> (row, chunk)
    const int srow   = lane >> 2;                       // 0..15
    const int schunk = (lane & 3) ^ ((srow >> 1) & 3);  // global-side swizzle
    const unsigned char* gA = Xn + (size_t)(rowBase + wave * 16 + srow) * KB + schunk * 16;
    const unsigned char* gB = Nn + (size_t)(colBase + wave * 16 + srow) * KB + schunk * 16;
    const int lgrp0 = (wave * 16) * BK;
    const int lgrp1 = (wave * 16 + 64) * BK;

    const f32x4 fz = {0.f, 0.f, 0.f, 0.f};
    f32x4 acc[4][4];
#pragma unroll
    for (int mi = 0; mi < 4; mi++)
#pragma unroll
        for (int ni = 0; ni < 4; ni++) acc[mi][ni] = fz;

    const int m0   = (wave >> 1) * 64;
    const int n0   = (wave & 1) * 64;
    const int quad = lane >> 4;          // k-group: k = ks2*32 + quad*8 + j
    const int mrow = lane & 15;
    const int kx   = (mrow >> 1) & 3;    // read-side swizzle key (row>>1)&3
    // k-step 0 chunk byte offset (k-step 1 = this ^ 32)
    const int cb0  = (((quad >> 1) ^ kx) << 4) + (quad & 1) * 8;

    int aoff[4], boff[4];
#pragma unroll
    for (int i = 0; i < 4; i++) {
        aoff[i] = (m0 + i * 16 + mrow) * BK + cb0;
        boff[i] = (n0 + i * 16 + mrow) * BK + cb0;
    }

#define STAGE(buf, stg)                                                  \
    do {                                                                 \
        const int kq = (stg) * BK;                                       \
        async_copy16(gA + kq,            &Ash[buf][lgrp0]);              \
        async_copy16(gA + 64 * KB + kq,  &Ash[buf][lgrp1]);              \
        async_copy16(gB + kq,            &Bsh[buf][lgrp0]);              \
        async_copy16(gB + 64 * KB + kq,  &Bsh[buf][lgrp1]);              \
    } while (0)

#define COMPUTE(buf)                                                     \
    do {                                                                 \
        _Pragma("unroll")                                                \
        for (int ks2 = 0; ks2 < 2; ks2++) {                              \
            const int cx = ks2 * 32;   /* k-step chunk flip */           \
            long af[4], bf[4];                                           \
            _Pragma("unroll")                                            \
            for (int i = 0; i < 4; i++) {                                \
                af[i] = *(const long*)&Ash[buf][aoff[i] ^ cx];           \
                bf[i] = *(const long*)&Bsh[buf][boff[i] ^ cx];           \
            }                                                            \
            _Pragma("unroll")                                            \
            for (int mi = 0; mi < 4; mi++)                               \
                _Pragma("unroll")                                        \
                for (int ni = 0; ni < 4; ni++)                           \
                    acc[mi][ni] = __builtin_amdgcn_mfma_f32_16x16x32_fp8_fp8( \
                        af[mi], bf[ni], acc[mi][ni], 0, 0, 0);           \
        }                                                                \
    } while (0)

    STAGE(0, 0);
    STAGE(1, 1);
    // 16 stages total; stage s computed at phase s in buffer s%3
    for (int it = 0; it < 4; it++) {
        const int s = 3 * it + 2;
        PIPE_SYNC(4); STAGE(2, s);     COMPUTE(0);
        PIPE_SYNC(4); STAGE(0, s + 1); COMPUTE(1);
        PIPE_SYNC(4); STAGE(1, s + 2); COMPUTE(2);
    }
    PIPE_SYNC(4); STAGE(2, 14); COMPUTE(0);   // stage 12
    PIPE_SYNC(4); STAGE(0, 15); COMPUTE(1);   // stage 13
    PIPE_SYNC(4);               COMPUTE(2);   // stage 14
    PIPE_SYNC(0);               COMPUTE(0);   // stage 15
#undef STAGE
#undef COMPUTE

    // epilogue: undo x16*x16 scaling (1/256), exp, 16-col reduce, atomics.
    // C/D layout: col=lane&15, row=quad*4+reg.
#pragma unroll
    for (int mi = 0; mi < 4; mi++) {
        float rs0 = 0.f, rs1 = 0.f, rs2 = 0.f, rs3 = 0.f;
#pragma unroll
        for (int ni = 0; ni < 4; ni++) {
            rs0 += __expf(acc[mi][ni].x * 0.00390625f);
            rs1 += __expf(acc[mi][ni].y * 0.00390625f);
            rs2 += __expf(acc[mi][ni].z * 0.00390625f);
            rs3 += __expf(acc[mi][ni].w * 0.00390625f);
        }
#pragma unroll
        for (int off = 1; off < 16; off <<= 1) {
            rs0 += __shfl_xor(rs0, off);
            rs1 += __shfl_xor(rs1, off);
            rs2 += __shfl_xor(rs2, off);
            rs3 += __shfl_xor(rs3, off);
        }
        if ((lane & 15) == 0) {
            const int r = rowBase + m0 + mi * 16 + quad * 4;
            atomicAdd(&rowsum[r + 0], rs0);
            atomicAdd(&rowsum[r + 1], rs1);
            atomicAdd(&rowsum[r + 2], rs2);
            atomicAdd(&rowsum[r + 3], rs3);
        }
    }
}

__global__ __launch_bounds__(1024)
void loss_kernel(const float* __restrict__ rowsum, const float* __restrict__ sim,
                 float* __restrict__ out, int bn) {
    const int tid  = threadIdx.x;
    const int lane = tid & 63;
    const int wave = tid >> 6;
    float acc = 0.f;
    for (int i = tid; i < bn; i += 1024) acc += logf(rowsum[i]) - sim[i];
#pragma unroll
    for (int off = 1; off < 64; off <<= 1) acc += __shfl_xor(acc, off);
    __shared__ float red[16];
    if (lane == 0) red[wave] = acc;
    __syncthreads();
    if (tid == 0) {
        float t = 0.f;
#pragma unroll
        for (int i = 0; i < 16; i++) t += red[i];
        out[0] = t / (float)bn;
    }
}

extern "C" void kernel_launch(void* const* d_in, const int* in_sizes, int n_in,
                              void* d_out, int out_size, void* d_ws, size_t ws_size,
                              hipStream_t stream) {
    const float* x   = (const float*)d_in[0];
    const float* pos = (const float*)d_in[1];
    const float* neg = (const float*)d_in[2];
    const int bn = in_sizes[0] / DIM;  // 4096
    const int cn = in_sizes[2] / DIM;  // 8192

    // ws layout: Xn fp8 [bn*DIM] | Nn fp8 [cn*DIM] | sim f32 [bn] | rowsum f32 [bn]
    unsigned char* Xn = (unsigned char*)d_ws;
    unsigned char* Nn = Xn + (size_t)bn * DIM;
    float* sim    = (float*)(Nn + (size_t)cn * DIM);
    float* rowsum = sim + bn;

    prep_all<<<dim3((bn + cn) / 4), dim3(256), 0, stream>>>(x, pos, neg, Xn, Nn, sim, rowsum, bn);
    gemm_exp_rowsum<<<dim3(cn / 128, bn / 128), dim3(256), 0, stream>>>(Xn, Nn, rowsum);
    loss_kernel<<<dim3(1), dim3(1024), 0, stream>>>(rowsum, sim, (float*)d_out, bn);
}

// Round 6
// 166.837 us; speedup vs baseline: 1.3409x; 1.0798x over previous
//
#include <hip/hip_runtime.h>
#include <stdint.h>
#include <stddef.h>

#define DIM 1024
#define EPS 1e-8f

typedef __attribute__((ext_vector_type(4))) float f32x4;
typedef __attribute__((ext_vector_type(2))) long longx2;   // 16 B = 2 fp8 k-halves

// async global->LDS, 16B per lane, wave-uniform LDS base + lane*16
__device__ __forceinline__ void async_copy16(const void* g, void* l) {
    __builtin_amdgcn_global_load_lds(
        (__attribute__((address_space(1))) void*)const_cast<void*>(g),
        (__attribute__((address_space(3))) void*)(l), 16, 0, 0);
}

// drain all but newest N vmem ops, then barrier
#define PIPE_SYNC(N) asm volatile("s_waitcnt vmcnt(" #N ")\n\ts_barrier" ::: "memory")

// ---------------------------------------------------------------------------
// Prep: wave-per-row. Unit-normalize, scale by 16 (undone in epilogue), cast
// to OCP fp8 e4m3. Rows are stored PERMUTED per 64-B k-window: 16-B chunk q
// holds bytes [q*8, q*8+8) and [32+q*8, +8) of the window — so the GEMM can
// fetch both k-steps of an MFMA quad-fragment with ONE ds_read_b128
// (the R3-verified conflict-free LDS pattern).
// Lane L owns bytes [16L,16L+16) = window s=L>>2, halves a0=(L&3)*2, a0+1.
// Permuted dests within window: d0=(m&1)*32+(m>>1)*8, d1=d0+16  (m=L&3).
// ---------------------------------------------------------------------------
__global__ __launch_bounds__(256)
void prep_all(const float* __restrict__ x, const float* __restrict__ pos,
              const float* __restrict__ neg,
              unsigned char* __restrict__ Xn, unsigned char* __restrict__ Nn,
              float* __restrict__ simOut, float* __restrict__ rowsum, int bn) {
    const int lane = threadIdx.x & 63;
    const int wave = threadIdx.x >> 6;
    const int grow = blockIdx.x * 4 + wave;
    const bool isX = grow < bn;
    const int row  = isX ? grow : grow - bn;
    const float* src = isX ? x : neg;
    unsigned char* dst = isX ? Xn : Nn;

    const float4* s = (const float4*)(src + (size_t)row * DIM);
    float4 xv[4], pv[4];
    float sxx = 0.f, spp = 0.f, sxp = 0.f;
#pragma unroll
    for (int i = 0; i < 4; i++) {
        xv[i] = s[lane + 64 * i];
        sxx += xv[i].x * xv[i].x + xv[i].y * xv[i].y + xv[i].z * xv[i].z + xv[i].w * xv[i].w;
    }
    if (isX) {
        const float4* p = (const float4*)(pos + (size_t)row * DIM);
#pragma unroll
        for (int i = 0; i < 4; i++) {
            pv[i] = p[lane + 64 * i];
            spp += pv[i].x * pv[i].x + pv[i].y * pv[i].y + pv[i].z * pv[i].z + pv[i].w * pv[i].w;
            sxp += xv[i].x * pv[i].x + xv[i].y * pv[i].y + xv[i].z * pv[i].z + xv[i].w * pv[i].w;
        }
#pragma unroll
        for (int off = 1; off < 64; off <<= 1) {
            sxx += __shfl_xor(sxx, off);
            spp += __shfl_xor(spp, off);
            sxp += __shfl_xor(sxp, off);
        }
    } else {
#pragma unroll
        for (int off = 1; off < 64; off <<= 1) sxx += __shfl_xor(sxx, off);
    }
    const float nx  = sqrtf(sxx);
    const float inv = (nx > 0.f) ? (16.f / nx) : 0.f;   // x16 -> e4m3 sweet spot
    if (isX && lane == 0) {
        const float np = sqrtf(spp);
        simOut[row] = sxp / fmaxf(nx * np, EPS);
        rowsum[row] = 0.f;
    }
    unsigned int t;
    t = __builtin_amdgcn_cvt_pk_fp8_f32(xv[0].x * inv, xv[0].y * inv, 0, false);
    unsigned int q0 = __builtin_amdgcn_cvt_pk_fp8_f32(xv[0].z * inv, xv[0].w * inv, t, true);
    t = __builtin_amdgcn_cvt_pk_fp8_f32(xv[1].x * inv, xv[1].y * inv, 0, false);
    unsigned int q1 = __builtin_amdgcn_cvt_pk_fp8_f32(xv[1].z * inv, xv[1].w * inv, t, true);
    t = __builtin_amdgcn_cvt_pk_fp8_f32(xv[2].x * inv, xv[2].y * inv, 0, false);
    unsigned int q2 = __builtin_amdgcn_cvt_pk_fp8_f32(xv[2].z * inv, xv[2].w * inv, t, true);
    t = __builtin_amdgcn_cvt_pk_fp8_f32(xv[3].x * inv, xv[3].y * inv, 0, false);
    unsigned int q3 = __builtin_amdgcn_cvt_pk_fp8_f32(xv[3].z * inv, xv[3].w * inv, t, true);

    const int m  = lane & 3;
    const int d0 = (m & 1) * 32 + (m >> 1) * 8;          // 0,32,8,40
    unsigned char* wbase = dst + (size_t)row * DIM + (lane >> 2) * 64;
    *(unsigned long long*)(wbase + d0)      = ((unsigned long long)q1 << 32) | q0;
    *(unsigned long long*)(wbase + d0 + 16) = ((unsigned long long)q3 << 32) | q2;
}

// ---------------------------------------------------------------------------
// Fused fp8 GEMM: rowsum[i] += sum_j exp( (Xn8[i]/16 . Nn8[j]/16) )
// 128x128 tile, BK=64 B (permuted windows), 3-stage LDS (48 KB), prefetch
// distance 2 via s_waitcnt vmcnt(4)+s_barrier. Per phase: 8 ds_read_b128
// (each feeds TWO mfma_f32_16x16x32_fp8_fp8 k-steps) + 32 MFMA.
// Chunk swizzle: physical chunk = logical ^ ((row>>1)&3) — with b128 reads
// this tiles all 32 banks per 16-lane group (R3-verified zero conflicts).
// ---------------------------------------------------------------------------
__global__ __launch_bounds__(256)
void gemm_exp_rowsum(const unsigned char* __restrict__ Xn,
                     const unsigned char* __restrict__ Nn,
                     float* __restrict__ rowsum) {
    constexpr int KB   = DIM;        // 1024 bytes per fp8 row
    constexpr int BK   = 64;         // bytes per stage-row (one permuted window)
    constexpr int BUFB = 128 * BK;   // 8 KB per buffer
    __shared__ __align__(16) unsigned char Ash[3][BUFB];
    __shared__ __align__(16) unsigned char Bsh[3][BUFB];

    const int tid  = threadIdx.x;
    const int lane = tid & 63;
    const int wave = tid >> 6;
    const int rowBase = blockIdx.y * 128;
    const int colBase = blockIdx.x * 128;

    // staging: one glds = 1 KB = 16 rows x 64 B; lane -> (row, chunk)
    const int srow   = lane >> 2;                       // 0..15
    const int schunk = (lane & 3) ^ ((srow >> 1) & 3);  // global-side swizzle
    const unsigned char* gA = Xn + (size_t)(rowBase + wave * 16 + srow) * KB + schunk * 16;
    const unsigned char* gB = Nn + (size_t)(colBase + wave * 16 + srow) * KB + schunk * 16;
    const int lgrp0 = (wave * 16) * BK;
    const int lgrp1 = (wave * 16 + 64) * BK;

    const f32x4 fz = {0.f, 0.f, 0.f, 0.f};
    f32x4 acc[4][4];
#pragma unroll
    for (int mi = 0; mi < 4; mi++)
#pragma unroll
        for (int ni = 0; ni < 4; ni++) acc[mi][ni] = fz;

    const int m0   = (wave >> 1) * 64;
    const int n0   = (wave & 1) * 64;
    const int quad = lane >> 4;          // fragment k-group
    const int mrow = lane & 15;
    const int kx   = (mrow >> 1) & 3;    // read-side swizzle key

    int aoff[4], boff[4];
#pragma unroll
    for (int i = 0; i < 4; i++) {
        aoff[i] = (m0 + i * 16 + mrow) * BK + ((quad ^ kx) << 4);
        boff[i] = (n0 + i * 16 + mrow) * BK + ((quad ^ kx) << 4);
    }

#define STAGE(buf, stg)                                                  \
    do {                                                                 \
        const int kq = (stg) * BK;                                       \
        async_copy16(gA + kq,            &Ash[buf][lgrp0]);              \
        async_copy16(gA + 64 * KB + kq,  &Ash[buf][lgrp1]);              \
        async_copy16(gB + kq,            &Bsh[buf][lgrp0]);              \
        async_copy16(gB + 64 * KB + kq,  &Bsh[buf][lgrp1]);              \
    } while (0)

#define COMPUTE(buf)                                                     \
    do {                                                                 \
        longx2 a2[4], b2[4];                                             \
        _Pragma("unroll")                                                \
        for (int i = 0; i < 4; i++) {                                    \
            a2[i] = *(const longx2*)&Ash[buf][aoff[i]];                  \
            b2[i] = *(const longx2*)&Bsh[buf][boff[i]];                  \
        }                                                                \
        _Pragma("unroll")                                                \
        for (int mi = 0; mi < 4; mi++)                                   \
            _Pragma("unroll")                                            \
            for (int ni = 0; ni < 4; ni++) {                             \
                acc[mi][ni] = __builtin_amdgcn_mfma_f32_16x16x32_fp8_fp8( \
                    a2[mi].x, b2[ni].x, acc[mi][ni], 0, 0, 0);           \
                acc[mi][ni] = __builtin_amdgcn_mfma_f32_16x16x32_fp8_fp8( \
                    a2[mi].y, b2[ni].y, acc[mi][ni], 0, 0, 0);           \
            }                                                            \
    } while (0)

    STAGE(0, 0);
    STAGE(1, 1);
    // 16 stages; stage s computed at phase s in buffer s%3, staged 2 ahead
    for (int it = 0; it < 4; it++) {
        const int s = 3 * it + 2;
        PIPE_SYNC(4); STAGE(2, s);     COMPUTE(0);
        PIPE_SYNC(4); STAGE(0, s + 1); COMPUTE(1);
        PIPE_SYNC(4); STAGE(1, s + 2); COMPUTE(2);
    }
    PIPE_SYNC(4); STAGE(2, 14); COMPUTE(0);   // stage 12
    PIPE_SYNC(4); STAGE(0, 15); COMPUTE(1);   // stage 13
    PIPE_SYNC(4);               COMPUTE(2);   // stage 14
    PIPE_SYNC(0);               COMPUTE(0);   // stage 15
#undef STAGE
#undef COMPUTE

    // epilogue: undo x16*x16 scaling (1/256), exp, 16-col reduce, atomics.
    // C/D layout: col=lane&15, row=quad*4+reg.
#pragma unroll
    for (int mi = 0; mi < 4; mi++) {
        float rs0 = 0.f, rs1 = 0.f, rs2 = 0.f, rs3 = 0.f;
#pragma unroll
        for (int ni = 0; ni < 4; ni++) {
            rs0 += __expf(acc[mi][ni].x * 0.00390625f);
            rs1 += __expf(acc[mi][ni].y * 0.00390625f);
            rs2 += __expf(acc[mi][ni].z * 0.00390625f);
            rs3 += __expf(acc[mi][ni].w * 0.00390625f);
        }
#pragma unroll
        for (int off = 1; off < 16; off <<= 1) {
            rs0 += __shfl_xor(rs0, off);
            rs1 += __shfl_xor(rs1, off);
            rs2 += __shfl_xor(rs2, off);
            rs3 += __shfl_xor(rs3, off);
        }
        if ((lane & 15) == 0) {
            const int r = rowBase + m0 + mi * 16 + quad * 4;
            atomicAdd(&rowsum[r + 0], rs0);
            atomicAdd(&rowsum[r + 1], rs1);
            atomicAdd(&rowsum[r + 2], rs2);
            atomicAdd(&rowsum[r + 3], rs3);
        }
    }
}

__global__ __launch_bounds__(1024)
void loss_kernel(const float* __restrict__ rowsum, const float* __restrict__ sim,
                 float* __restrict__ out, int bn) {
    const int tid  = threadIdx.x;
    const int lane = tid & 63;
    const int wave = tid >> 6;
    float acc = 0.f;
    for (int i = tid; i < bn; i += 1024) acc += logf(rowsum[i]) - sim[i];
#pragma unroll
    for (int off = 1; off < 64; off <<= 1) acc += __shfl_xor(acc, off);
    __shared__ float red[16];
    if (lane == 0) red[wave] = acc;
    __syncthreads();
    if (tid == 0) {
        float t = 0.f;
#pragma unroll
        for (int i = 0; i < 16; i++) t += red[i];
        out[0] = t / (float)bn;
    }
}

extern "C" void kernel_launch(void* const* d_in, const int* in_sizes, int n_in,
                              void* d_out, int out_size, void* d_ws, size_t ws_size,
                              hipStream_t stream) {
    const float* x   = (const float*)d_in[0];
    const float* pos = (const float*)d_in[1];
    const float* neg = (const float*)d_in[2];
    const int bn = in_sizes[0] / DIM;  // 4096
    const int cn = in_sizes[2] / DIM;  // 8192

    // ws layout: Xn fp8 [bn*DIM] | Nn fp8 [cn*DIM] | sim f32 [bn] | rowsum f32 [bn]
    unsigned char* Xn = (unsigned char*)d_ws;
    unsigned char* Nn = Xn + (size_t)bn * DIM;
    float* sim    = (float*)(Nn + (size_t)cn * DIM);
    float* rowsum = sim + bn;

    prep_all<<<dim3((bn + cn) / 4), dim3(256), 0, stream>>>(x, pos, neg, Xn, Nn, sim, rowsum, bn);
    gemm_exp_rowsum<<<dim3(cn / 128, bn / 128), dim3(256), 0, stream>>>(Xn, Nn, rowsum);
    loss_kernel<<<dim3(1), dim3(1024), 0, stream>>>(rowsum, sim, (float*)d_out, bn);
}